// Round 5
// baseline (957.987 us; speedup 1.0000x reference)
//
#include <hip/hip_runtime.h>
#include <hip/hip_bf16.h>

typedef __attribute__((ext_vector_type(8))) short bf16x8;
typedef __attribute__((ext_vector_type(4))) float f32x4;

#define DEVI __device__ __forceinline__

DEVI short f2bf(float f) {
  union { float f; unsigned u; } v; v.f = f;
  unsigned r = v.u + 0x7FFFu + ((v.u >> 16) & 1u);
  return (short)(r >> 16);
}

DEVI void gl16(const void* g, void* l) {
  __builtin_amdgcn_global_load_lds((const __attribute__((address_space(1))) unsigned*)g,
                                   (__attribute__((address_space(3))) unsigned*)l,
                                   16, 0, 0);
}

DEVI float exp2a(float x) { float r; asm("v_exp_f32 %0, %1" : "=v"(r) : "v"(x)); return r; }

DEVI unsigned pk2(float lo, float hi) {
  union { __hip_bfloat162 h; unsigned u; } v;
  float2 f; f.x = lo; f.y = hi;
  v.h = __float22bfloat162_rn(f);
  return v.u;
}

union U8 { unsigned u[4]; bf16x8 v; };
DEVI bf16x8 mk8(unsigned a, unsigned b, unsigned c, unsigned d) {
  U8 x; x.u[0]=a; x.u[1]=b; x.u[2]=c; x.u[3]=d; return x.v;
}

// ---------------- conversion kernels ----------------

__global__ __launch_bounds__(256) void conv_x_k(const float* __restrict__ x,
                                                short* __restrict__ xb) {
  long i = (long)blockIdx.x * 256 + threadIdx.x;
  const float4* xf = (const float4*)x;
  float4 a = xf[i * 2], c = xf[i * 2 + 1];
  bf16x8 r;
  r[0] = f2bf(a.x); r[1] = f2bf(a.y); r[2] = f2bf(a.z); r[3] = f2bf(a.w);
  r[4] = f2bf(c.x); r[5] = f2bf(c.y); r[6] = f2bf(c.z); r[7] = f2bf(c.w);
  *(bf16x8*)(xb + i * 8) = r;
}

__global__ __launch_bounds__(256) void conv_wT_k(const float* __restrict__ w,
                                                 short* __restrict__ wT, int Ncols) {
  int i = blockIdx.x * 256 + threadIdx.x;
  if (i >= Ncols * 512) return;
  int n = i >> 9, k = i & 511;
  wT[i] = f2bf(w[k * Ncols + n]);
}

// biasT[h][m][n] = btab[relidx(n_query, m_key)*16+h] * log2(e); -1e30 for m>=49
__global__ __launch_bounds__(256) void fill_biasT(const float* __restrict__ btab,
                                                  float* __restrict__ biasT) {
  int i = blockIdx.x * 256 + threadIdx.x;   // 16*64*64
  int h = i >> 12, m = (i >> 6) & 63, n = i & 63;
  float v;
  if (m >= 49) {
    v = -1e30f;
  } else {
    int nn = n > 48 ? 48 : n;
    int ni = nn / 7, nj = nn - ni * 7;
    int mi = m / 7,  mj = m - mi * 7;
    int idx = (ni - mi + 6) * 13 + (nj - mj + 6);
    v = btab[idx * 16 + h] * 1.4426950408889634f;
  }
  biasT[i] = v;
}

// ---------------- 256x256 bf16 GEMM, BK=64, dbuf prefetch, B^T input ----------------
// 8 waves (2 M-halves x 4 N-quarters), wave tile 128x64, 16x16x32 MFMA.
// LDS 128 KiB: 2 bufs x (A 256x64 + B 256x64) bf16, 128B rows of 8x16B chunks.
// Swizzle: LDS slot (row, c) holds global chunk c ^ (row&7); reads XOR likewise.
// K-tile kt+1 staged into buf^1 while computing kt; one __syncthreads per K-tile.

template <int EPI>
__global__ __launch_bounds__(512, 2)
void gemm256(const short* __restrict__ A, const short* __restrict__ Bt,
             const float* __restrict__ bias, void* __restrict__ outp, int ctiles) {
  __shared__ short Ls[65536];   // [2][A 16384 | B 16384] shorts

  const int nwg = gridDim.x;
  const int w = blockIdx.x;
  const int chunk = nwg >> 3;
  const int tid = (w & 7) * chunk + (w >> 3);    // XCD-contiguous remap (nwg%8==0)
  const int rt = tid / ctiles, ct = tid % ctiles;
  const long m0 = (long)rt * 256;
  const int n0 = ct * 256;

  const int t = threadIdx.x;          // 0..511
  const int lane = t & 63;
  const int wv = t >> 6;              // 0..7
  const int wr = wv >> 2;             // 0..1
  const int wc = wv & 3;              // 0..3
  const int l15 = lane & 15, g = lane >> 4;

  // staging map: shot s -> row s*64 + (t>>3), LDS chunk t&7, global chunk swizzled
  const int srow = t >> 3;
  const int gch = (t & 7) ^ (srow & 7);
  const short* Ag = A + (m0 + srow) * 512 + gch * 8;
  const short* Bg = Bt + (long)(n0 + srow) * 512 + gch * 8;

  // fragment read offsets (shorts): row*64 + ((ks*4+g)^ (l15&7))*8
  const int x7 = l15 & 7;
  const int c0 = (g ^ x7) * 8;
  const int c1 = ((4 + g) ^ x7) * 8;
  const int rA64 = (wr * 128 + l15) * 64;
  const int rB64 = (wc * 64 + l15) * 64 + 16384;

  f32x4 acc[8][4] = {};

  // prologue: stage kt=0 into buf0
  {
    short* Ad = Ls + t * 8;
    short* Bd = Ls + 16384 + t * 8;
#pragma unroll
    for (int s2 = 0; s2 < 4; ++s2) {
      gl16(Ag + s2 * 32768, Ad + s2 * 4096);
      gl16(Bg + s2 * 32768, Bd + s2 * 4096);
    }
  }
  __syncthreads();

  for (int kt = 0; kt < 8; ++kt) {
    const int cur = kt & 1;
    const short* Ab = Ls + cur * 32768;
    short* Ad = Ls + (cur ^ 1) * 32768 + t * 8;
    short* Bd = Ad + 16384;
    const short* Agk = Ag + (kt + 1) * 64;
    const short* Bgk = Bg + (kt + 1) * 64;

    bf16x8 af[8], bf[4];

    // ---- ks = 0 ----
#pragma unroll
    for (int mf = 0; mf < 8; ++mf) af[mf] = *(const bf16x8*)(Ab + rA64 + mf * 1024 + c0);
#pragma unroll
    for (int nf = 0; nf < 4; ++nf) bf[nf] = *(const bf16x8*)(Ab + rB64 + nf * 1024 + c0);
    if (kt < 7) {
#pragma unroll
      for (int s2 = 0; s2 < 4; ++s2) gl16(Agk + s2 * 32768, Ad + s2 * 4096);
    }
#pragma unroll
    for (int mf = 0; mf < 8; ++mf)
#pragma unroll
      for (int nf = 0; nf < 4; ++nf)
        acc[mf][nf] = __builtin_amdgcn_mfma_f32_16x16x32_bf16(af[mf], bf[nf], acc[mf][nf], 0, 0, 0);

    // ---- ks = 1 ----
#pragma unroll
    for (int mf = 0; mf < 8; ++mf) af[mf] = *(const bf16x8*)(Ab + rA64 + mf * 1024 + c1);
#pragma unroll
    for (int nf = 0; nf < 4; ++nf) bf[nf] = *(const bf16x8*)(Ab + rB64 + nf * 1024 + c1);
    if (kt < 7) {
#pragma unroll
      for (int s2 = 0; s2 < 4; ++s2) gl16(Bgk + s2 * 32768, Bd + s2 * 4096);
    }
#pragma unroll
    for (int mf = 0; mf < 8; ++mf)
#pragma unroll
      for (int nf = 0; nf < 4; ++nf)
        acc[mf][nf] = __builtin_amdgcn_mfma_f32_16x16x32_bf16(af[mf], bf[nf], acc[mf][nf], 0, 0, 0);

    __syncthreads();   // drains vmcnt: kt+1 landed; buf[cur] free for kt+2 staging
  }

  if (EPI == 0) {
    short* qkv = (short*)outp;
#pragma unroll
    for (int mf = 0; mf < 8; ++mf)
#pragma unroll
      for (int r = 0; r < 4; ++r) {
        int row = (int)m0 + wr * 128 + mf * 16 + g * 4 + r;
        int b = row / 49, n = row - b * 49;
#pragma unroll
        for (int nf = 0; nf < 4; ++nf) {
          int col = n0 + wc * 64 + nf * 16 + l15;
          float val = acc[mf][nf][r] + bias[col];
          int ii = col >> 9, h = (col >> 5) & 15, d = col & 31;
          qkv[(long)((b * 16 + h) * 3 + ii) * 1568 + n * 32 + d] = f2bf(val);
        }
      }
  } else {
    float* out = (float*)outp;
#pragma unroll
    for (int mf = 0; mf < 8; ++mf)
#pragma unroll
      for (int r = 0; r < 4; ++r) {
        long row = m0 + wr * 128 + mf * 16 + g * 4 + r;
#pragma unroll
        for (int nf = 0; nf < 4; ++nf) {
          int col = n0 + wc * 64 + nf * 16 + l15;
          out[row * 512 + col] = acc[mf][nf][r] + bias[col];
        }
      }
  }
}

// ---------------- attention: swapped-QK^T, in-register softmax, no LDS, no barriers ----

__global__ __launch_bounds__(256, 3)
void attn49(const short* __restrict__ qkvb, const float* __restrict__ biasT,
            short* __restrict__ ao) {
  const int t = threadIdx.x, lane = t & 63, wv = t >> 6;
  const int l15 = lane & 15, g = lane >> 4, g4 = g * 4;
  const int b = blockIdx.x >> 2;
  const int h = (blockIdx.x & 3) * 4 + wv;

  const short* qb = qkvb + (long)(b * 16 + h) * 3 * 1568;
  const short* kb = qb + 1568;
  const short* vb = kb + 1568;

  // Q/K fragments (rows clamped to 48; junk killed by bias)
  bf16x8 qf[4], kf[4];
#pragma unroll
  for (int i = 0; i < 4; ++i) {
    int row = i * 16 + l15; row = row > 48 ? 48 : row;
    kf[i] = *(const bf16x8*)(kb + row * 32 + g * 8);
    qf[i] = *(const bf16x8*)(qb + row * 32 + g * 8);
  }

  // V B-fragments: vf[kt][dt][e] = V[sigma(kt,g,e)][dt*16+l15], clamped
  bf16x8 vf[2][2];
#pragma unroll
  for (int kt = 0; kt < 2; ++kt)
#pragma unroll
    for (int hi = 0; hi < 2; ++hi)
#pragma unroll
      for (int r = 0; r < 4; ++r) {
        int m = kt * 32 + hi * 16 + g4 + r;
        m = m > 48 ? 48 : m;
#pragma unroll
        for (int dt = 0; dt < 2; ++dt)
          vf[kt][dt][hi * 4 + r] = vb[m * 32 + dt * 16 + l15];
      }

  // S = K·Q^T (swapped): rows m = key, cols n = query
  f32x4 s[4][4] = {};
#pragma unroll
  for (int i = 0; i < 4; ++i)
#pragma unroll
    for (int j = 0; j < 4; ++j)
      s[i][j] = __builtin_amdgcn_mfma_f32_16x16x32_bf16(kf[i], qf[j], s[i][j], 0, 0, 0);

  // p = exp2(s*scale*log2e + biasT); column sums (over m) in-lane + 2 shfl
  const float* biasH = biasT + h * 4096;
  float sum[4] = {0.f, 0.f, 0.f, 0.f};
#pragma unroll
  for (int i = 0; i < 4; ++i)
#pragma unroll
    for (int r = 0; r < 4; ++r) {
      int m = i * 16 + g4 + r;
      const float* bp = biasH + m * 64 + l15;
#pragma unroll
      for (int j = 0; j < 4; ++j) {
        float p = exp2a(fmaf(s[i][j][r], 0.06375871f, bp[j * 16]));
        s[i][j][r] = p;
        sum[j] += p;
      }
    }
#pragma unroll
  for (int j = 0; j < 4; ++j) {
    sum[j] += __shfl_xor(sum[j], 16);
    sum[j] += __shfl_xor(sum[j], 32);
    sum[j] = 1.f / sum[j];
  }

  // normalize + pack to bf16 pairs (pure in-lane)
  unsigned pk[4][4][2];
#pragma unroll
  for (int j = 0; j < 4; ++j)
#pragma unroll
    for (int i = 0; i < 4; ++i) {
      pk[j][i][0] = pk2(s[i][j][0] * sum[j], s[i][j][1] * sum[j]);
      pk[j][i][1] = pk2(s[i][j][2] * sum[j], s[i][j][3] * sum[j]);
    }

  // O = P·V
  f32x4 o[4][2] = {};
#pragma unroll
  for (int j = 0; j < 4; ++j) {
    bf16x8 a0 = mk8(pk[j][0][0], pk[j][0][1], pk[j][1][0], pk[j][1][1]);
    bf16x8 a1 = mk8(pk[j][2][0], pk[j][2][1], pk[j][3][0], pk[j][3][1]);
    o[j][0] = __builtin_amdgcn_mfma_f32_16x16x32_bf16(a0, vf[0][0], o[j][0], 0, 0, 0);
    o[j][0] = __builtin_amdgcn_mfma_f32_16x16x32_bf16(a1, vf[1][0], o[j][0], 0, 0, 0);
    o[j][1] = __builtin_amdgcn_mfma_f32_16x16x32_bf16(a0, vf[0][1], o[j][1], 0, 0, 0);
    o[j][1] = __builtin_amdgcn_mfma_f32_16x16x32_bf16(a1, vf[1][1], o[j][1], 0, 0, 0);
  }

  // write attn_out [M,512] bf16: col = h*32 + d
#pragma unroll
  for (int j = 0; j < 4; ++j)
#pragma unroll
    for (int r = 0; r < 4; ++r) {
      int n = j * 16 + g4 + r;
      if (n < 49) {
        long off = ((long)b * 49 + n) * 512 + h * 32 + l15;
        ao[off]      = f2bf(o[j][0][r]);
        ao[off + 16] = f2bf(o[j][1][r]);
      }
    }
}

// ---------------- host ----------------

extern "C" void kernel_launch(void* const* d_in, const int* in_sizes, int n_in,
                              void* d_out, int out_size, void* d_ws, size_t ws_size,
                              hipStream_t stream) {
  (void)in_sizes; (void)n_in; (void)out_size; (void)ws_size;
  const float* x      = (const float*)d_in[0];
  const float* w_qkv  = (const float*)d_in[1];
  const float* b_qkv  = (const float*)d_in[2];
  const float* w_proj = (const float*)d_in[3];
  const float* b_proj = (const float*)d_in[4];
  const float* btab   = (const float*)d_in[5];

  char* ws = (char*)d_ws;
  short* xb  = (short*)ws;                                        // 205,520,896 B
  short* wqT = (short*)(ws + 205520896L);                         //   1,572,864 B
  short* wpT = (short*)(ws + 205520896L + 1572864L);              //     524,288 B
  short* qkv = (short*)(ws + 205520896L + 1572864L + 524288L);    // 616,562,688 B
  short* ao  = xb;                     // alias: x_bf16 dead after QKV GEMM
  float* biasT = (float*)wqT;          // alias: wqT dead after QKV GEMM (256 KB)

  conv_x_k <<<50176, 256, 0, stream>>>(x, xb);
  conv_wT_k<<<3072, 256, 0, stream>>>(w_qkv, wqT, 1536);
  conv_wT_k<<<1024, 256, 0, stream>>>(w_proj, wpT, 512);
  gemm256<0><<<4704, 512, 0, stream>>>(xb, wqT, b_qkv, (void*)qkv, 6);
  fill_biasT<<<256, 256, 0, stream>>>(btab, biasT);
  attn49   <<<16384, 256, 0, stream>>>(qkv, biasT, ao);
  gemm256<1><<<1568, 512, 0, stream>>>(ao, wpT, b_proj, d_out, 2);
}

// Round 6
// 895.182 us; speedup vs baseline: 1.0702x; 1.0702x over previous
//
#include <hip/hip_runtime.h>
#include <hip/hip_bf16.h>

typedef __attribute__((ext_vector_type(8))) short bf16x8;
typedef __attribute__((ext_vector_type(4))) float f32x4;

#define DEVI __device__ __forceinline__

DEVI short f2bf(float f) {
  union { float f; unsigned u; } v; v.f = f;
  unsigned r = v.u + 0x7FFFu + ((v.u >> 16) & 1u);
  return (short)(r >> 16);
}

DEVI void gl16(const void* g, void* l) {
  __builtin_amdgcn_global_load_lds((const __attribute__((address_space(1))) unsigned*)g,
                                   (__attribute__((address_space(3))) unsigned*)l,
                                   16, 0, 0);
}

DEVI float exp2a(float x) { float r; asm("v_exp_f32 %0, %1" : "=v"(r) : "v"(x)); return r; }

DEVI unsigned pk2(float lo, float hi) {
  union { __hip_bfloat162 h; unsigned u; } v;
  float2 f; f.x = lo; f.y = hi;
  v.h = __float22bfloat162_rn(f);
  return v.u;
}

union U8 { unsigned u[4]; bf16x8 v; };
DEVI bf16x8 mk8(unsigned a, unsigned b, unsigned c, unsigned d) {
  U8 x; x.u[0]=a; x.u[1]=b; x.u[2]=c; x.u[3]=d; return x.v;
}

// ---------------- conversion kernels ----------------

__global__ __launch_bounds__(256) void conv_x_k(const float* __restrict__ x,
                                                short* __restrict__ xb) {
  long i = (long)blockIdx.x * 256 + threadIdx.x;
  const float4* xf = (const float4*)x;
  float4 a = xf[i * 2], c = xf[i * 2 + 1];
  bf16x8 r;
  r[0] = f2bf(a.x); r[1] = f2bf(a.y); r[2] = f2bf(a.z); r[3] = f2bf(a.w);
  r[4] = f2bf(c.x); r[5] = f2bf(c.y); r[6] = f2bf(c.z); r[7] = f2bf(c.w);
  *(bf16x8*)(xb + i * 8) = r;
}

__global__ __launch_bounds__(256) void conv_wT_k(const float* __restrict__ w,
                                                 short* __restrict__ wT, int Ncols) {
  int i = blockIdx.x * 256 + threadIdx.x;
  if (i >= Ncols * 512) return;
  int n = i >> 9, k = i & 511;
  wT[i] = f2bf(w[k * Ncols + n]);
}

// biasT[h][m][n] = btab[relidx(n_query, m_key)*16+h] * log2(e); -1e30 for m>=49
__global__ __launch_bounds__(256) void fill_biasT(const float* __restrict__ btab,
                                                  float* __restrict__ biasT) {
  int i = blockIdx.x * 256 + threadIdx.x;   // 16*64*64
  int h = i >> 12, m = (i >> 6) & 63, n = i & 63;
  float v;
  if (m >= 49) {
    v = -1e30f;
  } else {
    int nn = n > 48 ? 48 : n;
    int ni = nn / 7, nj = nn - ni * 7;
    int mi = m / 7,  mj = m - mi * 7;
    int idx = (ni - mi + 6) * 13 + (nj - mj + 6);
    v = btab[idx * 16 + h] * 1.4426950408889634f;
  }
  biasT[i] = v;
}

// ---------------- 256x256 bf16 GEMM, BK=64, 4-phase counted-vmcnt schedule ----------------
// 8 waves (2M x 4N), wave tile 128x64. LDS 128 KiB = 2 bufs x 4 regions x 16 KiB:
// regions (shorts): A_kh0 @0, A_kh1 @8192, B_kh0 @16384, B_kh1 @24576; rows 32 shorts.
// Swizzle (proven 0-conflict r4): slot (row,c) holds global chunk c^((row>>1)&3).
// Phase q = (kh=q>>1, nh=q&1): ds-read frags, stage ONE region of kt+1 into buf^1,
// [vmcnt(4) at q1,q3], s_barrier, setprio(1), 16 MFMA, setprio(0), s_barrier.
// vmcnt never drains to 0 in the loop (T4); loads span a full K-tile.

template <int EPI>
__global__ __launch_bounds__(512, 2)
void gemm256(const short* __restrict__ A, const short* __restrict__ Bt,
             const float* __restrict__ bias, void* __restrict__ outp, int ctiles) {
  __shared__ short Ls[65536];

  const int nwg = gridDim.x;
  const int w = blockIdx.x;
  const int chunk = nwg >> 3;
  const int tid = (w & 7) * chunk + (w >> 3);    // XCD-contiguous remap (nwg%8==0)
  const int rt = tid / ctiles, ct = tid % ctiles;
  const long m0 = (long)rt * 256;
  const int n0 = ct * 256;

  const int t = threadIdx.x;          // 0..511
  const int lane = t & 63;
  const int wv = t >> 6;
  const int wr = wv >> 2;             // 0..1  (M half)
  const int wc = wv & 3;              // 0..3  (N quarter)
  const int l15 = lane & 15, g = lane >> 4;

  // staging: thread t -> row t>>2 (+128 for 2nd gl16), LDS chunk t&3, global chunk swizzled
  const int gch = (t & 3) ^ ((t >> 3) & 3);
  const short* Ag = A + (m0 + (t >> 2)) * 512 + gch * 8;
  const short* Bg = Bt + (long)(n0 + (t >> 2)) * 512 + gch * 8;

  // fragment read chunk: (g ^ ((l15>>1)&3)) * 8 shorts
  const int cA = ((g ^ ((l15 >> 1) & 3))) * 8;
  const int rowA = (wr * 128 + l15) * 32;
  const int rowB = (wc * 64 + l15) * 32;

  f32x4 acc[8][4] = {};
  bf16x8 af[8], bfr[2];

#define STAGE_A(ktn, kh, bufn)                                         \
  { const short* s_ = Ag + (ktn) * 64 + (kh) * 32;                     \
    short* d_ = (bufn) + (kh) * 8192 + t * 8;                          \
    gl16(s_, d_); gl16(s_ + 128 * 512, d_ + 4096); }
#define STAGE_B(ktn, kh, bufn)                                         \
  { const short* s_ = Bg + (ktn) * 64 + (kh) * 32;                     \
    short* d_ = (bufn) + 16384 + (kh) * 8192 + t * 8;                  \
    gl16(s_, d_); gl16(s_ + 128 * 512, d_ + 4096); }
#define LOAD_AF(Ab, kh)                                                \
  _Pragma("unroll")                                                    \
  for (int mf = 0; mf < 8; ++mf)                                       \
    af[mf] = *(const bf16x8*)((Ab) + (kh) * 8192 + rowA + mf * 512 + cA);
#define LOAD_BF(Ab, kh, nh)                                            \
  bfr[0] = *(const bf16x8*)((Ab) + 16384 + (kh) * 8192 + rowB + ((nh) * 2) * 512 + cA); \
  bfr[1] = *(const bf16x8*)((Ab) + 16384 + (kh) * 8192 + rowB + ((nh) * 2 + 1) * 512 + cA);
#define MFMA16(nh)                                                     \
  __builtin_amdgcn_s_setprio(1);                                       \
  _Pragma("unroll")                                                    \
  for (int mf = 0; mf < 8; ++mf) {                                     \
    acc[mf][(nh) * 2] = __builtin_amdgcn_mfma_f32_16x16x32_bf16(af[mf], bfr[0], acc[mf][(nh) * 2], 0, 0, 0);         \
    acc[mf][(nh) * 2 + 1] = __builtin_amdgcn_mfma_f32_16x16x32_bf16(af[mf], bfr[1], acc[mf][(nh) * 2 + 1], 0, 0, 0); \
  }                                                                    \
  __builtin_amdgcn_s_setprio(0);
#define BAR() asm volatile("s_barrier" ::: "memory")
#define VMW4() asm volatile("s_waitcnt vmcnt(4)" ::: "memory")

  // prologue: stage kt0 (A0,B0,A1,B1); wait oldest 2 regions; barrier
  STAGE_A(0, 0, Ls); STAGE_B(0, 0, Ls); STAGE_A(0, 1, Ls); STAGE_B(0, 1, Ls);
  VMW4();
  BAR();

  for (int kt = 0; kt < 8; ++kt) {
    const short* Ab = Ls + (kt & 1) * 32768;
    short* Bn = Ls + ((kt & 1) ^ 1) * 32768;
    const int ktn = kt < 7 ? kt + 1 : 7;   // last tile: re-stage (dead buf, valid addrs)

    // phase 0: kh0 nh0
    LOAD_AF(Ab, 0); LOAD_BF(Ab, 0, 0);
    STAGE_A(ktn, 0, Bn);
    BAR(); MFMA16(0); BAR();

    // phase 1: kh0 nh1
    LOAD_BF(Ab, 0, 1);
    STAGE_B(ktn, 0, Bn);
    VMW4();
    BAR(); MFMA16(1); BAR();

    // phase 2: kh1 nh0
    LOAD_AF(Ab, 1); LOAD_BF(Ab, 1, 0);
    STAGE_A(ktn, 1, Bn);
    BAR(); MFMA16(0); BAR();

    // phase 3: kh1 nh1
    LOAD_BF(Ab, 1, 1);
    STAGE_B(ktn, 1, Bn);
    VMW4();
    BAR(); MFMA16(1); BAR();
  }

  if (EPI == 0) {
    short* qkv = (short*)outp;
#pragma unroll
    for (int mf = 0; mf < 8; ++mf)
#pragma unroll
      for (int r = 0; r < 4; ++r) {
        int row = (int)m0 + wr * 128 + mf * 16 + g * 4 + r;
        int b = row / 49, n = row - b * 49;
#pragma unroll
        for (int nf = 0; nf < 4; ++nf) {
          int col = n0 + wc * 64 + nf * 16 + l15;
          float val = acc[mf][nf][r] + bias[col];
          int ii = col >> 9, h = (col >> 5) & 15, d = col & 31;
          qkv[(long)((b * 16 + h) * 3 + ii) * 1568 + n * 32 + d] = f2bf(val);
        }
      }
  } else {
    float* out = (float*)outp;
#pragma unroll
    for (int mf = 0; mf < 8; ++mf)
#pragma unroll
      for (int r = 0; r < 4; ++r) {
        long row = m0 + wr * 128 + mf * 16 + g * 4 + r;
#pragma unroll
        for (int nf = 0; nf < 4; ++nf) {
          int col = n0 + wc * 64 + nf * 16 + l15;
          out[row * 512 + col] = acc[mf][nf][r] + bias[col];
        }
      }
  }
#undef STAGE_A
#undef STAGE_B
#undef LOAD_AF
#undef LOAD_BF
#undef MFMA16
#undef BAR
#undef VMW4
}

// ---------------- attention: swapped-QK^T, in-register softmax, no LDS, no barriers ----

__global__ __launch_bounds__(256, 3)
void attn49(const short* __restrict__ qkvb, const float* __restrict__ biasT,
            short* __restrict__ ao) {
  const int t = threadIdx.x, lane = t & 63, wv = t >> 6;
  const int l15 = lane & 15, g = lane >> 4, g4 = g * 4;
  const int b = blockIdx.x >> 2;
  const int h = (blockIdx.x & 3) * 4 + wv;

  const short* qb = qkvb + (long)(b * 16 + h) * 3 * 1568;
  const short* kb = qb + 1568;
  const short* vb = kb + 1568;

  // Q/K fragments (rows clamped to 48; junk killed by bias)
  bf16x8 qf[4], kf[4];
#pragma unroll
  for (int i = 0; i < 4; ++i) {
    int row = i * 16 + l15; row = row > 48 ? 48 : row;
    kf[i] = *(const bf16x8*)(kb + row * 32 + g * 8);
    qf[i] = *(const bf16x8*)(qb + row * 32 + g * 8);
  }

  // V B-fragments: vf[kt][dt][e] = V[sigma(kt,g,e)][dt*16+l15], clamped
  bf16x8 vf[2][2];
#pragma unroll
  for (int kt = 0; kt < 2; ++kt)
#pragma unroll
    for (int hi = 0; hi < 2; ++hi)
#pragma unroll
      for (int r = 0; r < 4; ++r) {
        int m = kt * 32 + hi * 16 + g4 + r;
        m = m > 48 ? 48 : m;
#pragma unroll
        for (int dt = 0; dt < 2; ++dt)
          vf[kt][dt][hi * 4 + r] = vb[m * 32 + dt * 16 + l15];
      }

  // S = K·Q^T (swapped): rows m = key, cols n = query
  f32x4 s[4][4] = {};
#pragma unroll
  for (int i = 0; i < 4; ++i)
#pragma unroll
    for (int j = 0; j < 4; ++j)
      s[i][j] = __builtin_amdgcn_mfma_f32_16x16x32_bf16(kf[i], qf[j], s[i][j], 0, 0, 0);

  // p = exp2(s*scale*log2e + biasT); column sums (over m) in-lane + 2 shfl
  const float* biasH = biasT + h * 4096;
  float sum[4] = {0.f, 0.f, 0.f, 0.f};
#pragma unroll
  for (int i = 0; i < 4; ++i)
#pragma unroll
    for (int r = 0; r < 4; ++r) {
      int m = i * 16 + g4 + r;
      const float* bp = biasH + m * 64 + l15;
#pragma unroll
      for (int j = 0; j < 4; ++j) {
        float p = exp2a(fmaf(s[i][j][r], 0.06375871f, bp[j * 16]));
        s[i][j][r] = p;
        sum[j] += p;
      }
    }
#pragma unroll
  for (int j = 0; j < 4; ++j) {
    sum[j] += __shfl_xor(sum[j], 16);
    sum[j] += __shfl_xor(sum[j], 32);
    sum[j] = 1.f / sum[j];
  }

  // normalize + pack to bf16 pairs (pure in-lane)
  unsigned pk[4][4][2];
#pragma unroll
  for (int j = 0; j < 4; ++j)
#pragma unroll
    for (int i = 0; i < 4; ++i) {
      pk[j][i][0] = pk2(s[i][j][0] * sum[j], s[i][j][1] * sum[j]);
      pk[j][i][1] = pk2(s[i][j][2] * sum[j], s[i][j][3] * sum[j]);
    }

  // O = P·V
  f32x4 o[4][2] = {};
#pragma unroll
  for (int j = 0; j < 4; ++j) {
    bf16x8 a0 = mk8(pk[j][0][0], pk[j][0][1], pk[j][1][0], pk[j][1][1]);
    bf16x8 a1 = mk8(pk[j][2][0], pk[j][2][1], pk[j][3][0], pk[j][3][1]);
    o[j][0] = __builtin_amdgcn_mfma_f32_16x16x32_bf16(a0, vf[0][0], o[j][0], 0, 0, 0);
    o[j][0] = __builtin_amdgcn_mfma_f32_16x16x32_bf16(a1, vf[1][0], o[j][0], 0, 0, 0);
    o[j][1] = __builtin_amdgcn_mfma_f32_16x16x32_bf16(a0, vf[0][1], o[j][1], 0, 0, 0);
    o[j][1] = __builtin_amdgcn_mfma_f32_16x16x32_bf16(a1, vf[1][1], o[j][1], 0, 0, 0);
  }

  // write attn_out [M,512] bf16: col = h*32 + d
#pragma unroll
  for (int j = 0; j < 4; ++j)
#pragma unroll
    for (int r = 0; r < 4; ++r) {
      int n = j * 16 + g4 + r;
      if (n < 49) {
        long off = ((long)b * 49 + n) * 512 + h * 32 + l15;
        ao[off]      = f2bf(o[j][0][r]);
        ao[off + 16] = f2bf(o[j][1][r]);
      }
    }
}

// ---------------- host ----------------

extern "C" void kernel_launch(void* const* d_in, const int* in_sizes, int n_in,
                              void* d_out, int out_size, void* d_ws, size_t ws_size,
                              hipStream_t stream) {
  (void)in_sizes; (void)n_in; (void)out_size; (void)ws_size;
  const float* x      = (const float*)d_in[0];
  const float* w_qkv  = (const float*)d_in[1];
  const float* b_qkv  = (const float*)d_in[2];
  const float* w_proj = (const float*)d_in[3];
  const float* b_proj = (const float*)d_in[4];
  const float* btab   = (const float*)d_in[5];

  char* ws = (char*)d_ws;
  short* xb  = (short*)ws;                                        // 205,520,896 B
  short* wqT = (short*)(ws + 205520896L);                         //   1,572,864 B
  short* wpT = (short*)(ws + 205520896L + 1572864L);              //     524,288 B
  short* qkv = (short*)(ws + 205520896L + 1572864L + 524288L);    // 616,562,688 B
  short* ao  = xb;                     // alias: x_bf16 dead after QKV GEMM
  float* biasT = (float*)wqT;          // alias: wqT dead after QKV GEMM (256 KB)

  conv_x_k <<<50176, 256, 0, stream>>>(x, xb);
  conv_wT_k<<<3072, 256, 0, stream>>>(w_qkv, wqT, 1536);
  conv_wT_k<<<1024, 256, 0, stream>>>(w_proj, wpT, 512);
  gemm256<0><<<4704, 512, 0, stream>>>(xb, wqT, b_qkv, (void*)qkv, 6);
  fill_biasT<<<256, 256, 0, stream>>>(btab, biasT);
  attn49   <<<16384, 256, 0, stream>>>(qkv, biasT, ao);
  gemm256<1><<<1568, 512, 0, stream>>>(ao, wpT, b_proj, d_out, 2);
}